// Round 2
// baseline (867.586 us; speedup 1.0000x reference)
//
#include <hip/hip_runtime.h>
#include <hip/hip_bf16.h>
#include <stdint.h>

#define D_DIM 1024
#define B_DIM 8
#define T_DIM 2048
#define M_DIM (B_DIM * T_DIM)  // 16384

typedef __attribute__((ext_vector_type(8))) short bf16x8;
typedef __attribute__((ext_vector_type(4))) float f32x4;

__device__ __forceinline__ unsigned short f2bf(float f) {
    union { float f; uint32_t u; } c; c.f = f;
    uint32_t u = c.u;
    u += 0x7fffu + ((u >> 16) & 1u);
    return (unsigned short)(u >> 16);
}
__device__ __forceinline__ float bf2f(unsigned short h) {
    union { uint32_t u; float f; } c; c.u = ((uint32_t)h) << 16;
    return c.f;
}

// ---------------- W [K,N] fp32 -> WT [N,K] bf16 ----------------
__global__ void transpose_to_bf16(const float* __restrict__ W,
                                  unsigned short* __restrict__ WT) {
    __shared__ float tile[32][33];
    int tx = threadIdx.x, ty = threadIdx.y;
    int x0 = blockIdx.x * 32, y0 = blockIdx.y * 32;
#pragma unroll
    for (int i = 0; i < 4; i++) {
        int r = ty + i * 8;
        tile[r][tx] = W[(size_t)(y0 + r) * D_DIM + x0 + tx];
    }
    __syncthreads();
#pragma unroll
    for (int i = 0; i < 4; i++) {
        int r = ty + i * 8;
        WT[(size_t)(x0 + r) * D_DIM + y0 + tx] = f2bf(tile[tx][r]);
    }
}

// ---------------- token-shift lerp, fp32 -> bf16 xk/xv/xr ----------------
__global__ void lerp_kernel(const float* __restrict__ x,
                            const float* __restrict__ last_x,
                            const float* __restrict__ tmk,
                            const float* __restrict__ tmv,
                            const float* __restrict__ tmr,
                            unsigned short* __restrict__ xk,
                            unsigned short* __restrict__ xv,
                            unsigned short* __restrict__ xr) {
    int gid = blockIdx.x * blockDim.x + threadIdx.x;  // 0 .. 4M-1
    size_t e = (size_t)gid * 4;
    int m = (int)(e >> 10);
    int c = (int)(e & 1023);
    int t = m & (T_DIM - 1);
    int b = m >> 11;
    float4 xc = *(const float4*)(x + e);
    float4 xp;
    if (t == 0) xp = *(const float4*)(last_x + (size_t)b * D_DIM + c);
    else        xp = *(const float4*)(x + e - D_DIM);
    float4 mk = *(const float4*)(tmk + c);
    float4 mv = *(const float4*)(tmv + c);
    float4 mr = *(const float4*)(tmr + c);

    ushort4 ok, ov, orr;
    ok.x = f2bf(xp.x + mk.x * (xc.x - xp.x));
    ok.y = f2bf(xp.y + mk.y * (xc.y - xp.y));
    ok.z = f2bf(xp.z + mk.z * (xc.z - xp.z));
    ok.w = f2bf(xp.w + mk.w * (xc.w - xp.w));
    ov.x = f2bf(xp.x + mv.x * (xc.x - xp.x));
    ov.y = f2bf(xp.y + mv.y * (xc.y - xp.y));
    ov.z = f2bf(xp.z + mv.z * (xc.z - xp.z));
    ov.w = f2bf(xp.w + mv.w * (xc.w - xp.w));
    orr.x = f2bf(xp.x + mr.x * (xc.x - xp.x));
    orr.y = f2bf(xp.y + mr.y * (xc.y - xp.y));
    orr.z = f2bf(xp.z + mr.z * (xc.z - xp.z));
    orr.w = f2bf(xp.w + mr.w * (xc.w - xp.w));
    *(ushort4*)(xk + e) = ok;
    *(ushort4*)(xv + e) = ov;
    *(ushort4*)(xr + e) = orr;
}

// ---------------- bf16 MFMA GEMM: C[M,N] = A[M,K] * BT[N,K]^T ----------------
// MODE 0: bf16 out, plain; MODE 1: bf16 out, sigmoid; MODE 2: fp32 out, plain
template <int MODE>
__global__ __launch_bounds__(256) void gemm_bf16(
    const unsigned short* __restrict__ A,
    const unsigned short* __restrict__ BT,
    void* __restrict__ Cout) {
    // padded stride 40 elems (80B): fragment ds_read_b128 spreads banks
    __shared__ __align__(16) unsigned short As[128 * 40];
    __shared__ __align__(16) unsigned short Bs[128 * 40];
    int tid = threadIdx.x;
    int wave = tid >> 6, lane = tid & 63;
    int wr = wave >> 1, wc = wave & 1;
    int l16 = lane & 15, q = lane >> 4;
    int m0 = blockIdx.y * 128, n0 = blockIdx.x * 128;

    f32x4 acc[4][4] = {};

    for (int k0 = 0; k0 < D_DIM; k0 += 32) {
        // stage 128x32 bf16 tile: 4096 elems = 2 iters x 256 thr x 8 elems
#pragma unroll
        for (int i = 0; i < 2; i++) {
            int eidx = (i * 256 + tid) * 8;   // 0..4095
            int r = eidx >> 5, c = eidx & 31; // r in 0..127
            *(uint4*)(&As[r * 40 + c]) =
                *(const uint4*)(A + (size_t)(m0 + r) * D_DIM + k0 + c);
            *(uint4*)(&Bs[r * 40 + c]) =
                *(const uint4*)(BT + (size_t)(n0 + r) * D_DIM + k0 + c);
        }
        __syncthreads();

        bf16x8 af[4], bfr[4];
#pragma unroll
        for (int mi = 0; mi < 4; mi++)
            af[mi] = *(const bf16x8*)(&As[(wr * 64 + mi * 16 + l16) * 40 + q * 8]);
#pragma unroll
        for (int ni = 0; ni < 4; ni++)
            bfr[ni] = *(const bf16x8*)(&Bs[(wc * 64 + ni * 16 + l16) * 40 + q * 8]);
#pragma unroll
        for (int mi = 0; mi < 4; mi++)
#pragma unroll
            for (int ni = 0; ni < 4; ni++)
                acc[mi][ni] = __builtin_amdgcn_mfma_f32_16x16x32_bf16(
                    af[mi], bfr[ni], acc[mi][ni], 0, 0, 0);
        __syncthreads();
    }

#pragma unroll
    for (int mi = 0; mi < 4; mi++) {
#pragma unroll
        for (int ni = 0; ni < 4; ni++) {
#pragma unroll
            for (int reg = 0; reg < 4; reg++) {
                int row = m0 + wr * 64 + mi * 16 + q * 4 + reg;
                int col = n0 + wc * 64 + ni * 16 + l16;
                float val = acc[mi][ni][reg];
                if (MODE == 1) val = 1.0f / (1.0f + __expf(-val));
                if (MODE == 2)
                    ((float*)Cout)[(size_t)row * D_DIM + col] = val;
                else
                    ((unsigned short*)Cout)[(size_t)row * D_DIM + col] = f2bf(val);
            }
        }
    }
}

// ---------------- WKV sequential scan ----------------
__global__ void wkv_scan(const unsigned short* __restrict__ kbuf,
                         const unsigned short* __restrict__ vbuf,
                         const unsigned short* __restrict__ rbuf,
                         const float* __restrict__ x,
                         const float* __restrict__ aa_in,
                         const float* __restrict__ bb_in,
                         const float* __restrict__ pp_in,
                         const float* __restrict__ time_first,
                         const float* __restrict__ time_decay,
                         unsigned short* __restrict__ rwkv,
                         float* __restrict__ lastx_out,
                         float* __restrict__ aa_out,
                         float* __restrict__ bb_out,
                         float* __restrict__ pp_out) {
    int gid = blockIdx.x * blockDim.x + threadIdx.x;  // 0..8191
    int b = gid >> 10, d = gid & 1023;
    float aa = aa_in[gid], bb = bb_in[gid], pp = pp_in[gid];
    float tf = time_first[d], td = time_decay[d];
    size_t base = (size_t)b * T_DIM * D_DIM + d;
    for (int t = 0; t < T_DIM; t++) {
        size_t idx = base + (size_t)t * D_DIM;
        float kt = bf2f(kbuf[idx]);
        float vt = bf2f(vbuf[idx]);
        float rt = bf2f(rbuf[idx]);
        float ww = tf + kt;
        float qq = fmaxf(pp, ww);
        float e1 = __expf(pp - qq);
        float e2 = __expf(ww - qq);
        float wkv = (e1 * aa + e2 * vt) / (e1 * bb + e2);
        rwkv[idx] = f2bf(rt * wkv);
        float ww2 = pp + td;
        float qq2 = fmaxf(ww2, kt);
        float e1b = __expf(ww2 - qq2);
        float e2b = __expf(kt - qq2);
        aa = e1b * aa + e2b * vt;
        bb = e1b * bb + e2b;
        pp = qq2;
    }
    aa_out[gid] = aa;
    bb_out[gid] = bb;
    pp_out[gid] = pp;
    lastx_out[gid] = x[base + (size_t)(T_DIM - 1) * D_DIM];
}

extern "C" void kernel_launch(void* const* d_in, const int* in_sizes, int n_in,
                              void* d_out, int out_size, void* d_ws,
                              size_t ws_size, hipStream_t stream) {
    const float* x      = (const float*)d_in[0];
    const float* last_x = (const float*)d_in[1];
    const float* aa     = (const float*)d_in[2];
    const float* bb     = (const float*)d_in[3];
    const float* pp     = (const float*)d_in[4];
    const float* tmk    = (const float*)d_in[5];
    const float* tmv    = (const float*)d_in[6];
    const float* tmr    = (const float*)d_in[7];
    const float* tf     = (const float*)d_in[8];
    const float* td     = (const float*)d_in[9];
    const float* Wk     = (const float*)d_in[10];
    const float* Wv     = (const float*)d_in[11];
    const float* Wr     = (const float*)d_in[12];
    const float* Wo     = (const float*)d_in[13];

    // workspace layout (bf16 elements), total 136 MB
    unsigned short* WkT = (unsigned short*)d_ws;
    unsigned short* WvT = WkT + (size_t)D_DIM * D_DIM;
    unsigned short* WrT = WvT + (size_t)D_DIM * D_DIM;
    unsigned short* WoT = WrT + (size_t)D_DIM * D_DIM;
    unsigned short* xk  = WoT + (size_t)D_DIM * D_DIM;
    unsigned short* xv  = xk + (size_t)M_DIM * D_DIM;
    unsigned short* xr  = xv + (size_t)M_DIM * D_DIM;
    unsigned short* kb  = xr + (size_t)M_DIM * D_DIM;
    unsigned short* vb   = xk;  // xk dead after GEMM-k
    unsigned short* rb   = xv;  // xv dead after GEMM-v
    unsigned short* rwkv = xr;  // xr dead after GEMM-r

    float* out       = (float*)d_out;
    float* lastx_out = out + (size_t)M_DIM * D_DIM;
    float* aa_out    = lastx_out + B_DIM * D_DIM;
    float* bb_out    = aa_out + B_DIM * D_DIM;
    float* pp_out    = bb_out + B_DIM * D_DIM;

    dim3 tb(32, 8), tg(32, 32);
    transpose_to_bf16<<<tg, tb, 0, stream>>>(Wk, WkT);
    transpose_to_bf16<<<tg, tb, 0, stream>>>(Wv, WvT);
    transpose_to_bf16<<<tg, tb, 0, stream>>>(Wr, WrT);
    transpose_to_bf16<<<tg, tb, 0, stream>>>(Wo, WoT);

    lerp_kernel<<<(M_DIM * D_DIM / 4) / 256, 256, 0, stream>>>(
        x, last_x, tmk, tmv, tmr, xk, xv, xr);

    dim3 gg(D_DIM / 128, M_DIM / 128);  // (8, 128)
    gemm_bf16<0><<<gg, 256, 0, stream>>>(xk, WkT, kb);
    gemm_bf16<0><<<gg, 256, 0, stream>>>(xv, WvT, vb);
    gemm_bf16<1><<<gg, 256, 0, stream>>>(xr, WrT, rb);

    wkv_scan<<<(B_DIM * D_DIM) / 256, 256, 0, stream>>>(
        kb, vb, rb, x, aa, bb, pp, tf, td, rwkv,
        lastx_out, aa_out, bb_out, pp_out);

    gemm_bf16<2><<<gg, 256, 0, stream>>>(rwkv, WoT, out);
}

// Round 3
// 462.617 us; speedup vs baseline: 1.8754x; 1.8754x over previous
//
#include <hip/hip_runtime.h>
#include <hip/hip_bf16.h>
#include <stdint.h>

#define D_DIM 1024
#define B_DIM 8
#define T_DIM 2048
#define M_DIM (B_DIM * T_DIM)  // 16384
#define CHUNK 32
#define NCHUNK (T_DIM / CHUNK)  // 64
#define NCH (B_DIM * D_DIM)     // 8192 channels

typedef __attribute__((ext_vector_type(8))) short bf16x8;
typedef __attribute__((ext_vector_type(4))) float f32x4;

__device__ __forceinline__ unsigned short f2bf(float f) {
    union { float f; uint32_t u; } c; c.f = f;
    uint32_t u = c.u;
    u += 0x7fffu + ((u >> 16) & 1u);
    return (unsigned short)(u >> 16);
}
__device__ __forceinline__ float bf2f(unsigned short h) {
    union { uint32_t u; float f; } c; c.u = ((uint32_t)h) << 16;
    return c.f;
}

// ---------------- W [K,N] fp32 -> WT [N,K] bf16 ----------------
__global__ void transpose_to_bf16(const float* __restrict__ W,
                                  unsigned short* __restrict__ WT) {
    __shared__ float tile[32][33];
    int tx = threadIdx.x, ty = threadIdx.y;
    int x0 = blockIdx.x * 32, y0 = blockIdx.y * 32;
#pragma unroll
    for (int i = 0; i < 4; i++) {
        int r = ty + i * 8;
        tile[r][tx] = W[(size_t)(y0 + r) * D_DIM + x0 + tx];
    }
    __syncthreads();
#pragma unroll
    for (int i = 0; i < 4; i++) {
        int r = ty + i * 8;
        WT[(size_t)(x0 + r) * D_DIM + y0 + tx] = f2bf(tile[tx][r]);
    }
}

// ---------------- token-shift lerp, fp32 -> bf16 xk/xv/xr ----------------
__global__ void lerp_kernel(const float* __restrict__ x,
                            const float* __restrict__ last_x,
                            const float* __restrict__ tmk,
                            const float* __restrict__ tmv,
                            const float* __restrict__ tmr,
                            unsigned short* __restrict__ xk,
                            unsigned short* __restrict__ xv,
                            unsigned short* __restrict__ xr) {
    int gid = blockIdx.x * blockDim.x + threadIdx.x;  // 0 .. 4M-1
    size_t e = (size_t)gid * 4;
    int m = (int)(e >> 10);
    int c = (int)(e & 1023);
    int t = m & (T_DIM - 1);
    int b = m >> 11;
    float4 xc = *(const float4*)(x + e);
    float4 xp;
    if (t == 0) xp = *(const float4*)(last_x + (size_t)b * D_DIM + c);
    else        xp = *(const float4*)(x + e - D_DIM);
    float4 mk = *(const float4*)(tmk + c);
    float4 mv = *(const float4*)(tmv + c);
    float4 mr = *(const float4*)(tmr + c);

    ushort4 ok, ov, orr;
    ok.x = f2bf(xp.x + mk.x * (xc.x - xp.x));
    ok.y = f2bf(xp.y + mk.y * (xc.y - xp.y));
    ok.z = f2bf(xp.z + mk.z * (xc.z - xp.z));
    ok.w = f2bf(xp.w + mk.w * (xc.w - xp.w));
    ov.x = f2bf(xp.x + mv.x * (xc.x - xp.x));
    ov.y = f2bf(xp.y + mv.y * (xc.y - xp.y));
    ov.z = f2bf(xp.z + mv.z * (xc.z - xp.z));
    ov.w = f2bf(xp.w + mv.w * (xc.w - xp.w));
    orr.x = f2bf(xp.x + mr.x * (xc.x - xp.x));
    orr.y = f2bf(xp.y + mr.y * (xc.y - xp.y));
    orr.z = f2bf(xp.z + mr.z * (xc.z - xp.z));
    orr.w = f2bf(xp.w + mr.w * (xc.w - xp.w));
    *(ushort4*)(xk + e) = ok;
    *(ushort4*)(xv + e) = ov;
    *(ushort4*)(xr + e) = orr;
}

// ---------------- bf16 MFMA GEMM: C[M,N] = A[M,K] * BT[N,K]^T ----------------
// MODE 0: bf16 out, plain; MODE 1: bf16 out, sigmoid; MODE 2: fp32 out, plain
template <int MODE>
__global__ __launch_bounds__(256) void gemm_bf16(
    const unsigned short* __restrict__ A,
    const unsigned short* __restrict__ BT,
    void* __restrict__ Cout) {
    __shared__ __align__(16) unsigned short As[128 * 40];
    __shared__ __align__(16) unsigned short Bs[128 * 40];
    int tid = threadIdx.x;
    int wave = tid >> 6, lane = tid & 63;
    int wr = wave >> 1, wc = wave & 1;
    int l16 = lane & 15, q = lane >> 4;
    int m0 = blockIdx.y * 128, n0 = blockIdx.x * 128;

    f32x4 acc[4][4] = {};

    for (int k0 = 0; k0 < D_DIM; k0 += 32) {
#pragma unroll
        for (int i = 0; i < 2; i++) {
            int eidx = (i * 256 + tid) * 8;   // 0..4095
            int r = eidx >> 5, c = eidx & 31; // r in 0..127
            *(uint4*)(&As[r * 40 + c]) =
                *(const uint4*)(A + (size_t)(m0 + r) * D_DIM + k0 + c);
            *(uint4*)(&Bs[r * 40 + c]) =
                *(const uint4*)(BT + (size_t)(n0 + r) * D_DIM + k0 + c);
        }
        __syncthreads();

        bf16x8 af[4], bfr[4];
#pragma unroll
        for (int mi = 0; mi < 4; mi++)
            af[mi] = *(const bf16x8*)(&As[(wr * 64 + mi * 16 + l16) * 40 + q * 8]);
#pragma unroll
        for (int ni = 0; ni < 4; ni++)
            bfr[ni] = *(const bf16x8*)(&Bs[(wc * 64 + ni * 16 + l16) * 40 + q * 8]);
#pragma unroll
        for (int mi = 0; mi < 4; mi++)
#pragma unroll
            for (int ni = 0; ni < 4; ni++)
                acc[mi][ni] = __builtin_amdgcn_mfma_f32_16x16x32_bf16(
                    af[mi], bfr[ni], acc[mi][ni], 0, 0, 0);
        __syncthreads();
    }

#pragma unroll
    for (int mi = 0; mi < 4; mi++) {
#pragma unroll
        for (int ni = 0; ni < 4; ni++) {
#pragma unroll
            for (int reg = 0; reg < 4; reg++) {
                int row = m0 + wr * 64 + mi * 16 + q * 4 + reg;
                int col = n0 + wc * 64 + ni * 16 + l16;
                float val = acc[mi][ni][reg];
                if (MODE == 1) val = 1.0f / (1.0f + __expf(-val));
                if (MODE == 2)
                    ((float*)Cout)[(size_t)row * D_DIM + col] = val;
                else
                    ((unsigned short*)Cout)[(size_t)row * D_DIM + col] = f2bf(val);
            }
        }
    }
}

// ---------------- WKV chunked scan ----------------
// phase 1: per (chunk, channel) local state from empty
__global__ void wkv_phase1(const unsigned short* __restrict__ kbuf,
                           const unsigned short* __restrict__ vbuf,
                           const float* __restrict__ td_arr,
                           float* __restrict__ laa,
                           float* __restrict__ lbb,
                           float* __restrict__ lpp) {
    int g = blockIdx.x * blockDim.x + threadIdx.x;  // 0 .. NCH*NCHUNK-1
    int ch = g & (NCH - 1);
    int c = g >> 13;  // chunk index (NCH = 8192 = 2^13)
    int d = ch & (D_DIM - 1);
    int b = ch >> 10;
    float td = td_arr[d];
    float aa = 0.f, bb = 0.f, pp = -1e30f;
    size_t base = (size_t)b * T_DIM * D_DIM + (size_t)(c * CHUNK) * D_DIM + d;
    for (int t = 0; t < CHUNK; t++) {
        size_t idx = base + (size_t)t * D_DIM;
        float kt = bf2f(kbuf[idx]);
        float vt = bf2f(vbuf[idx]);
        float ww2 = pp + td;
        float qq2 = fmaxf(ww2, kt);
        float e1b = __expf(ww2 - qq2);
        float e2b = __expf(kt - qq2);
        aa = e1b * aa + e2b * vt;
        bb = e1b * bb + e2b;
        pp = qq2;
    }
    laa[g] = aa;
    lbb[g] = bb;
    lpp[g] = pp;
}

// phase 2: combine chunk states sequentially; in-place local -> prefix
__global__ void wkv_phase2(const float* __restrict__ aa_in,
                           const float* __restrict__ bb_in,
                           const float* __restrict__ pp_in,
                           const float* __restrict__ td_arr,
                           const float* __restrict__ x,
                           float* __restrict__ laa,
                           float* __restrict__ lbb,
                           float* __restrict__ lpp,
                           float* __restrict__ lastx_out,
                           float* __restrict__ aa_out,
                           float* __restrict__ bb_out,
                           float* __restrict__ pp_out) {
    int ch = blockIdx.x * blockDim.x + threadIdx.x;  // 0..8191
    int d = ch & (D_DIM - 1);
    int b = ch >> 10;
    float td = td_arr[d];
    float Ldecay = (float)CHUNK * td;
    float A = aa_in[ch], Bv = bb_in[ch], P = pp_in[ch];
    for (int c = 0; c < NCHUNK; c++) {
        int idx = c * NCH + ch;
        float la = laa[idx], lb = lbb[idx], lp = lpp[idx];
        laa[idx] = A; lbb[idx] = Bv; lpp[idx] = P;  // prefix for chunk c
        float Pd = P + Ldecay;
        float q = fmaxf(Pd, lp);
        float e1 = __expf(Pd - q);
        float e2 = __expf(lp - q);
        A = e1 * A + e2 * la;
        Bv = e1 * Bv + e2 * lb;
        P = q;
    }
    aa_out[ch] = A;
    bb_out[ch] = Bv;
    pp_out[ch] = P;
    lastx_out[ch] =
        x[(size_t)b * T_DIM * D_DIM + (size_t)(T_DIM - 1) * D_DIM + d];
}

// phase 3: replay each chunk from its prefix state, emit r*wkv
__global__ void wkv_phase3(const unsigned short* __restrict__ kbuf,
                           const unsigned short* __restrict__ vbuf,
                           const unsigned short* __restrict__ rbuf,
                           const float* __restrict__ tf_arr,
                           const float* __restrict__ td_arr,
                           const float* __restrict__ laa,
                           const float* __restrict__ lbb,
                           const float* __restrict__ lpp,
                           unsigned short* __restrict__ rwkv) {
    int g = blockIdx.x * blockDim.x + threadIdx.x;
    int ch = g & (NCH - 1);
    int c = g >> 13;
    int d = ch & (D_DIM - 1);
    int b = ch >> 10;
    float tf = tf_arr[d], td = td_arr[d];
    float aa = laa[g], bb = lbb[g], pp = lpp[g];
    size_t base = (size_t)b * T_DIM * D_DIM + (size_t)(c * CHUNK) * D_DIM + d;
    for (int t = 0; t < CHUNK; t++) {
        size_t idx = base + (size_t)t * D_DIM;
        float kt = bf2f(kbuf[idx]);
        float vt = bf2f(vbuf[idx]);
        float rt = bf2f(rbuf[idx]);
        float ww = tf + kt;
        float qq = fmaxf(pp, ww);
        float e1 = __expf(pp - qq);
        float e2 = __expf(ww - qq);
        float wkv = (e1 * aa + e2 * vt) / (e1 * bb + e2);
        rwkv[idx] = f2bf(rt * wkv);
        float ww2 = pp + td;
        float qq2 = fmaxf(ww2, kt);
        float e1b = __expf(ww2 - qq2);
        float e2b = __expf(kt - qq2);
        aa = e1b * aa + e2b * vt;
        bb = e1b * bb + e2b;
        pp = qq2;
    }
}

extern "C" void kernel_launch(void* const* d_in, const int* in_sizes, int n_in,
                              void* d_out, int out_size, void* d_ws,
                              size_t ws_size, hipStream_t stream) {
    const float* x      = (const float*)d_in[0];
    const float* last_x = (const float*)d_in[1];
    const float* aa     = (const float*)d_in[2];
    const float* bb     = (const float*)d_in[3];
    const float* pp     = (const float*)d_in[4];
    const float* tmk    = (const float*)d_in[5];
    const float* tmv    = (const float*)d_in[6];
    const float* tmr    = (const float*)d_in[7];
    const float* tf     = (const float*)d_in[8];
    const float* td     = (const float*)d_in[9];
    const float* Wk     = (const float*)d_in[10];
    const float* Wv     = (const float*)d_in[11];
    const float* Wr     = (const float*)d_in[12];
    const float* Wo     = (const float*)d_in[13];

    // workspace layout (bf16 elements), total 136 MB
    unsigned short* WkT = (unsigned short*)d_ws;
    unsigned short* WvT = WkT + (size_t)D_DIM * D_DIM;
    unsigned short* WrT = WvT + (size_t)D_DIM * D_DIM;
    unsigned short* WoT = WrT + (size_t)D_DIM * D_DIM;
    unsigned short* xk  = WoT + (size_t)D_DIM * D_DIM;
    unsigned short* xv  = xk + (size_t)M_DIM * D_DIM;
    unsigned short* xr  = xv + (size_t)M_DIM * D_DIM;
    unsigned short* kb  = xr + (size_t)M_DIM * D_DIM;
    unsigned short* vb   = xk;  // xk dead after GEMM-k
    unsigned short* rb   = xv;  // xv dead after GEMM-v
    unsigned short* rwkv = xr;  // xr dead after GEMM-r

    // chunk-state arrays alias the dead Wk/Wv/Wr transposed buffers:
    // each is NCH*NCHUNK = 524288 floats = 2 MB = exactly one 1024x1024 bf16 W
    float* laa = (float*)WkT;
    float* lbb = (float*)WvT;
    float* lpp = (float*)WrT;

    float* out       = (float*)d_out;
    float* lastx_out = out + (size_t)M_DIM * D_DIM;
    float* aa_out    = lastx_out + B_DIM * D_DIM;
    float* bb_out    = aa_out + B_DIM * D_DIM;
    float* pp_out    = bb_out + B_DIM * D_DIM;

    dim3 tb(32, 8), tg(32, 32);
    transpose_to_bf16<<<tg, tb, 0, stream>>>(Wk, WkT);
    transpose_to_bf16<<<tg, tb, 0, stream>>>(Wv, WvT);
    transpose_to_bf16<<<tg, tb, 0, stream>>>(Wr, WrT);
    transpose_to_bf16<<<tg, tb, 0, stream>>>(Wo, WoT);

    lerp_kernel<<<(M_DIM * D_DIM / 4) / 256, 256, 0, stream>>>(
        x, last_x, tmk, tmv, tmr, xk, xv, xr);

    dim3 gg(D_DIM / 128, M_DIM / 128);  // (8, 128)
    gemm_bf16<0><<<gg, 256, 0, stream>>>(xk, WkT, kb);
    gemm_bf16<0><<<gg, 256, 0, stream>>>(xv, WvT, vb);
    gemm_bf16<1><<<gg, 256, 0, stream>>>(xr, WrT, rb);

    // chunked WKV scan (laa/lbb/lpp overwrite WkT/WvT/WrT — dead by now)
    wkv_phase1<<<(NCH * NCHUNK) / 256, 256, 0, stream>>>(kb, vb, td, laa, lbb, lpp);
    wkv_phase2<<<NCH / 256, 256, 0, stream>>>(aa, bb, pp, td, x, laa, lbb, lpp,
                                              lastx_out, aa_out, bb_out, pp_out);
    wkv_phase3<<<(NCH * NCHUNK) / 256, 256, 0, stream>>>(
        kb, vb, rb, tf, td, laa, lbb, lpp, rwkv);

    gemm_bf16<2><<<gg, 256, 0, stream>>>(rwkv, WoT, out);
}

// Round 4
// 417.913 us; speedup vs baseline: 2.0760x; 1.1070x over previous
//
#include <hip/hip_runtime.h>
#include <hip/hip_bf16.h>
#include <stdint.h>

#define D_DIM 1024
#define B_DIM 8
#define T_DIM 2048
#define M_DIM (B_DIM * T_DIM)  // 16384
#define CHUNK 32
#define NCHUNK (T_DIM / CHUNK)  // 64
#define NCH (B_DIM * D_DIM)     // 8192 channels

typedef __attribute__((ext_vector_type(8))) short bf16x8;
typedef __attribute__((ext_vector_type(4))) float f32x4;

__device__ __forceinline__ unsigned short f2bf(float f) {
    union { float f; uint32_t u; } c; c.f = f;
    uint32_t u = c.u;
    u += 0x7fffu + ((u >> 16) & 1u);
    return (unsigned short)(u >> 16);
}
__device__ __forceinline__ float bf2f(unsigned short h) {
    union { uint32_t u; float f; } c; c.u = ((uint32_t)h) << 16;
    return c.f;
}

// async global->LDS, 16B per lane; LDS dest = wave-uniform base + lane*16
__device__ __forceinline__ void gload_lds16(const unsigned short* g,
                                            unsigned short* lds_base) {
    __builtin_amdgcn_global_load_lds(
        (const __attribute__((address_space(1))) unsigned int*)g,
        (__attribute__((address_space(3))) unsigned int*)lds_base, 16, 0, 0);
}

// ---------------- 4x W [K,N] fp32 -> WT [N,K] bf16 (fused, z selects W) ----
__global__ void transpose_to_bf16(const float* __restrict__ W0,
                                  const float* __restrict__ W1,
                                  const float* __restrict__ W2,
                                  const float* __restrict__ W3,
                                  unsigned short* __restrict__ WT0,
                                  unsigned short* __restrict__ WT1,
                                  unsigned short* __restrict__ WT2,
                                  unsigned short* __restrict__ WT3) {
    const float* W = (blockIdx.z == 0) ? W0 : (blockIdx.z == 1) ? W1
                     : (blockIdx.z == 2) ? W2 : W3;
    unsigned short* WT = (blockIdx.z == 0) ? WT0 : (blockIdx.z == 1) ? WT1
                         : (blockIdx.z == 2) ? WT2 : WT3;
    __shared__ float tile[32][33];
    int tx = threadIdx.x, ty = threadIdx.y;
    int x0 = blockIdx.x * 32, y0 = blockIdx.y * 32;
#pragma unroll
    for (int i = 0; i < 4; i++) {
        int r = ty + i * 8;
        tile[r][tx] = W[(size_t)(y0 + r) * D_DIM + x0 + tx];
    }
    __syncthreads();
#pragma unroll
    for (int i = 0; i < 4; i++) {
        int r = ty + i * 8;
        WT[(size_t)(x0 + r) * D_DIM + y0 + tx] = f2bf(tile[tx][r]);
    }
}

// ---------------- token-shift lerp, fp32 -> bf16 xk/xv/xr ----------------
__global__ void lerp_kernel(const float* __restrict__ x,
                            const float* __restrict__ last_x,
                            const float* __restrict__ tmk,
                            const float* __restrict__ tmv,
                            const float* __restrict__ tmr,
                            unsigned short* __restrict__ xk,
                            unsigned short* __restrict__ xv,
                            unsigned short* __restrict__ xr) {
    int gid = blockIdx.x * blockDim.x + threadIdx.x;  // 0 .. 4M-1
    size_t e = (size_t)gid * 4;
    int m = (int)(e >> 10);
    int c = (int)(e & 1023);
    int t = m & (T_DIM - 1);
    int b = m >> 11;
    float4 xc = *(const float4*)(x + e);
    float4 xp;
    if (t == 0) xp = *(const float4*)(last_x + (size_t)b * D_DIM + c);
    else        xp = *(const float4*)(x + e - D_DIM);
    float4 mk = *(const float4*)(tmk + c);
    float4 mv = *(const float4*)(tmv + c);
    float4 mr = *(const float4*)(tmr + c);

    ushort4 ok, ov, orr;
    ok.x = f2bf(xp.x + mk.x * (xc.x - xp.x));
    ok.y = f2bf(xp.y + mk.y * (xc.y - xp.y));
    ok.z = f2bf(xp.z + mk.z * (xc.z - xp.z));
    ok.w = f2bf(xp.w + mk.w * (xc.w - xp.w));
    ov.x = f2bf(xp.x + mv.x * (xc.x - xp.x));
    ov.y = f2bf(xp.y + mv.y * (xc.y - xp.y));
    ov.z = f2bf(xp.z + mv.z * (xc.z - xp.z));
    ov.w = f2bf(xp.w + mv.w * (xc.w - xp.w));
    orr.x = f2bf(xp.x + mr.x * (xc.x - xp.x));
    orr.y = f2bf(xp.y + mr.y * (xc.y - xp.y));
    orr.z = f2bf(xp.z + mr.z * (xc.z - xp.z));
    orr.w = f2bf(xp.w + mr.w * (xc.w - xp.w));
    *(ushort4*)(xk + e) = ok;
    *(ushort4*)(xv + e) = ov;
    *(ushort4*)(xr + e) = orr;
}

// ---------------- bf16 MFMA GEMM (m97 structure): C = A * BT^T -------------
// grid.x = m-tile (128), grid.y = n-tile (8) — same-A blocks share an XCD L2.
// MODE 0: bf16 out; MODE 1: bf16 out + sigmoid; MODE 2: fp32 out
template <int MODE>
__global__ __launch_bounds__(256) void gemm_bf16(
    const unsigned short* __restrict__ A,
    const unsigned short* __restrict__ BT,
    void* __restrict__ Cout) {
    // unpadded stride-32: required by global_load_lds lane-contiguous landing
    __shared__ __align__(16) unsigned short As[128 * 32];
    __shared__ __align__(16) unsigned short Bs[128 * 32];
    int tid = threadIdx.x;
    int wave = tid >> 6, lane = tid & 63;
    int wr = wave >> 1, wc = wave & 1;
    int l16 = lane & 15, q = lane >> 4;
    int m0 = blockIdx.x * 128, n0 = blockIdx.y * 128;

    // staging geometry: elem idx e = (i*256 + tid)*8; row = e>>5, col = e&31
    int r0 = tid >> 2, c0 = (tid & 3) * 8;        // i=0 rows 0..63
    int r1 = 64 + r0, c1 = c0;                    // i=1 rows 64..127
    unsigned short* lA0 = &As[wave * 512];        // wave-uniform bases
    unsigned short* lA1 = &As[2048 + wave * 512];
    unsigned short* lB0 = &Bs[wave * 512];
    unsigned short* lB1 = &Bs[2048 + wave * 512];
    const unsigned short* gA0 = A + (size_t)(m0 + r0) * D_DIM + c0;
    const unsigned short* gA1 = A + (size_t)(m0 + r1) * D_DIM + c1;
    const unsigned short* gB0 = BT + (size_t)(n0 + r0) * D_DIM + c0;
    const unsigned short* gB1 = BT + (size_t)(n0 + r1) * D_DIM + c1;

    f32x4 acc[4][4] = {};

    for (int k0 = 0; k0 < D_DIM; k0 += 32) {
        gload_lds16(gA0 + k0, lA0);
        gload_lds16(gA1 + k0, lA1);
        gload_lds16(gB0 + k0, lB0);
        gload_lds16(gB1 + k0, lB1);
        __syncthreads();  // drains vmcnt before barrier

        bf16x8 af[4], bfr[4];
#pragma unroll
        for (int mi = 0; mi < 4; mi++)
            af[mi] = *(const bf16x8*)(&As[(wr * 64 + mi * 16 + l16) * 32 + q * 8]);
#pragma unroll
        for (int ni = 0; ni < 4; ni++)
            bfr[ni] = *(const bf16x8*)(&Bs[(wc * 64 + ni * 16 + l16) * 32 + q * 8]);
#pragma unroll
        for (int mi = 0; mi < 4; mi++)
#pragma unroll
            for (int ni = 0; ni < 4; ni++)
                acc[mi][ni] = __builtin_amdgcn_mfma_f32_16x16x32_bf16(
                    af[mi], bfr[ni], acc[mi][ni], 0, 0, 0);
        __syncthreads();
    }

#pragma unroll
    for (int mi = 0; mi < 4; mi++) {
#pragma unroll
        for (int ni = 0; ni < 4; ni++) {
#pragma unroll
            for (int reg = 0; reg < 4; reg++) {
                int row = m0 + wr * 64 + mi * 16 + q * 4 + reg;
                int col = n0 + wc * 64 + ni * 16 + l16;
                float val = acc[mi][ni][reg];
                if (MODE == 1) val = 1.0f / (1.0f + __expf(-val));
                if (MODE == 2)
                    ((float*)Cout)[(size_t)row * D_DIM + col] = val;
                else
                    ((unsigned short*)Cout)[(size_t)row * D_DIM + col] = f2bf(val);
            }
        }
    }
}

// ---------------- WKV chunked scan ----------------
__global__ void wkv_phase1(const unsigned short* __restrict__ kbuf,
                           const unsigned short* __restrict__ vbuf,
                           const float* __restrict__ td_arr,
                           float* __restrict__ laa,
                           float* __restrict__ lbb,
                           float* __restrict__ lpp) {
    int g = blockIdx.x * blockDim.x + threadIdx.x;
    int ch = g & (NCH - 1);
    int c = g >> 13;
    int d = ch & (D_DIM - 1);
    int b = ch >> 10;
    float td = td_arr[d];
    float aa = 0.f, bb = 0.f, pp = -1e30f;
    size_t base = (size_t)b * T_DIM * D_DIM + (size_t)(c * CHUNK) * D_DIM + d;
    for (int t = 0; t < CHUNK; t++) {
        size_t idx = base + (size_t)t * D_DIM;
        float kt = bf2f(kbuf[idx]);
        float vt = bf2f(vbuf[idx]);
        float ww2 = pp + td;
        float qq2 = fmaxf(ww2, kt);
        float e1b = __expf(ww2 - qq2);
        float e2b = __expf(kt - qq2);
        aa = e1b * aa + e2b * vt;
        bb = e1b * bb + e2b;
        pp = qq2;
    }
    laa[g] = aa;
    lbb[g] = bb;
    lpp[g] = pp;
}

__global__ void wkv_phase2(const float* __restrict__ aa_in,
                           const float* __restrict__ bb_in,
                           const float* __restrict__ pp_in,
                           const float* __restrict__ td_arr,
                           const float* __restrict__ x,
                           float* __restrict__ laa,
                           float* __restrict__ lbb,
                           float* __restrict__ lpp,
                           float* __restrict__ lastx_out,
                           float* __restrict__ aa_out,
                           float* __restrict__ bb_out,
                           float* __restrict__ pp_out) {
    int ch = blockIdx.x * blockDim.x + threadIdx.x;
    int d = ch & (D_DIM - 1);
    int b = ch >> 10;
    float td = td_arr[d];
    float Ldecay = (float)CHUNK * td;
    float A = aa_in[ch], Bv = bb_in[ch], P = pp_in[ch];
    for (int c = 0; c < NCHUNK; c++) {
        int idx = c * NCH + ch;
        float la = laa[idx], lb = lbb[idx], lp = lpp[idx];
        laa[idx] = A; lbb[idx] = Bv; lpp[idx] = P;
        float Pd = P + Ldecay;
        float q = fmaxf(Pd, lp);
        float e1 = __expf(Pd - q);
        float e2 = __expf(lp - q);
        A = e1 * A + e2 * la;
        Bv = e1 * Bv + e2 * lb;
        P = q;
    }
    aa_out[ch] = A;
    bb_out[ch] = Bv;
    pp_out[ch] = P;
    lastx_out[ch] =
        x[(size_t)b * T_DIM * D_DIM + (size_t)(T_DIM - 1) * D_DIM + d];
}

__global__ void wkv_phase3(const unsigned short* __restrict__ kbuf,
                           const unsigned short* __restrict__ vbuf,
                           const unsigned short* __restrict__ rbuf,
                           const float* __restrict__ tf_arr,
                           const float* __restrict__ td_arr,
                           const float* __restrict__ laa,
                           const float* __restrict__ lbb,
                           const float* __restrict__ lpp,
                           unsigned short* __restrict__ rwkv) {
    int g = blockIdx.x * blockDim.x + threadIdx.x;
    int ch = g & (NCH - 1);
    int c = g >> 13;
    int d = ch & (D_DIM - 1);
    int b = ch >> 10;
    float tf = tf_arr[d], td = td_arr[d];
    float aa = laa[g], bb = lbb[g], pp = lpp[g];
    size_t base = (size_t)b * T_DIM * D_DIM + (size_t)(c * CHUNK) * D_DIM + d;
    for (int t = 0; t < CHUNK; t++) {
        size_t idx = base + (size_t)t * D_DIM;
        float kt = bf2f(kbuf[idx]);
        float vt = bf2f(vbuf[idx]);
        float rt = bf2f(rbuf[idx]);
        float ww = tf + kt;
        float qq = fmaxf(pp, ww);
        float e1 = __expf(pp - qq);
        float e2 = __expf(ww - qq);
        float wkv = (e1 * aa + e2 * vt) / (e1 * bb + e2);
        rwkv[idx] = f2bf(rt * wkv);
        float ww2 = pp + td;
        float qq2 = fmaxf(ww2, kt);
        float e1b = __expf(ww2 - qq2);
        float e2b = __expf(kt - qq2);
        aa = e1b * aa + e2b * vt;
        bb = e1b * bb + e2b;
        pp = qq2;
    }
}

extern "C" void kernel_launch(void* const* d_in, const int* in_sizes, int n_in,
                              void* d_out, int out_size, void* d_ws,
                              size_t ws_size, hipStream_t stream) {
    const float* x      = (const float*)d_in[0];
    const float* last_x = (const float*)d_in[1];
    const float* aa     = (const float*)d_in[2];
    const float* bb     = (const float*)d_in[3];
    const float* pp     = (const float*)d_in[4];
    const float* tmk    = (const float*)d_in[5];
    const float* tmv    = (const float*)d_in[6];
    const float* tmr    = (const float*)d_in[7];
    const float* tf     = (const float*)d_in[8];
    const float* td     = (const float*)d_in[9];
    const float* Wk     = (const float*)d_in[10];
    const float* Wv     = (const float*)d_in[11];
    const float* Wr     = (const float*)d_in[12];
    const float* Wo     = (const float*)d_in[13];

    unsigned short* WkT = (unsigned short*)d_ws;
    unsigned short* WvT = WkT + (size_t)D_DIM * D_DIM;
    unsigned short* WrT = WvT + (size_t)D_DIM * D_DIM;
    unsigned short* WoT = WrT + (size_t)D_DIM * D_DIM;
    unsigned short* xk  = WoT + (size_t)D_DIM * D_DIM;
    unsigned short* xv  = xk + (size_t)M_DIM * D_DIM;
    unsigned short* xr  = xv + (size_t)M_DIM * D_DIM;
    unsigned short* kb  = xr + (size_t)M_DIM * D_DIM;
    unsigned short* vb   = xk;  // xk dead after GEMM-k
    unsigned short* rb   = xv;  // xv dead after GEMM-v
    unsigned short* rwkv = xr;  // xr dead after GEMM-r

    float* laa = (float*)WkT;   // chunk states alias dead W^T buffers
    float* lbb = (float*)WvT;
    float* lpp = (float*)WrT;

    float* out       = (float*)d_out;
    float* lastx_out = out + (size_t)M_DIM * D_DIM;
    float* aa_out    = lastx_out + B_DIM * D_DIM;
    float* bb_out    = aa_out + B_DIM * D_DIM;
    float* pp_out    = bb_out + B_DIM * D_DIM;

    dim3 tb(32, 8), tg(32, 32, 4);
    transpose_to_bf16<<<tg, tb, 0, stream>>>(Wk, Wv, Wr, Wo, WkT, WvT, WrT, WoT);

    lerp_kernel<<<(M_DIM * D_DIM / 4) / 256, 256, 0, stream>>>(
        x, last_x, tmk, tmv, tmr, xk, xv, xr);

    dim3 gg(M_DIM / 128, D_DIM / 128);  // (128, 8) m-major
    gemm_bf16<0><<<gg, 256, 0, stream>>>(xk, WkT, kb);
    gemm_bf16<0><<<gg, 256, 0, stream>>>(xv, WvT, vb);
    gemm_bf16<1><<<gg, 256, 0, stream>>>(xr, WrT, rb);

    wkv_phase1<<<(NCH * NCHUNK) / 256, 256, 0, stream>>>(kb, vb, td, laa, lbb, lpp);
    wkv_phase2<<<NCH / 256, 256, 0, stream>>>(aa, bb, pp, td, x, laa, lbb, lpp,
                                              lastx_out, aa_out, bb_out, pp_out);
    wkv_phase3<<<(NCH * NCHUNK) / 256, 256, 0, stream>>>(
        kb, vb, rb, tf, td, laa, lbb, lpp, rwkv);

    gemm_bf16<2><<<gg, 256, 0, stream>>>(rwkv, WoT, out);
}